// Round 1
// baseline (607.479 us; speedup 1.0000x reference)
//
#include <hip/hip_runtime.h>
#include <hip/hip_bf16.h>
#include <cstdint>
#include <cstddef>

#define BROWS  16384
#define DDIM   1024
#define HID_N  4096
#define HALF_K 512

typedef __attribute__((ext_vector_type(8))) short s8v;
typedef __attribute__((ext_vector_type(4))) float f4v;

__device__ __forceinline__ void gload16(const void* g, void* l) {
  __builtin_amdgcn_global_load_lds(
      (const __attribute__((address_space(1))) unsigned int*)g,
      (__attribute__((address_space(3))) unsigned int*)l, 16, 0, 0);
}

// ---- prep: a16[m][k] = bf16(z[m][2k]) --------------------------------------
__global__ __launch_bounds__(256) void cast_a_kernel(const float* __restrict__ z,
                                                     __hip_bfloat16* __restrict__ a16) {
  const int idx = blockIdx.x * 256 + threadIdx.x;   // over M * (HALF/8)
  const int m  = idx >> 6;                          // HALF/8 == 64
  const int kb = idx & 63;
  const float4* zp = (const float4*)(z + (size_t)m * DDIM + (size_t)kb * 16);
  alignas(16) __hip_bfloat16 t[8];
#pragma unroll
  for (int i = 0; i < 4; ++i) {
    float4 v = zp[i];
    t[2 * i]     = __float2bfloat16(v.x);
    t[2 * i + 1] = __float2bfloat16(v.z);
  }
  *(s8v*)(a16 + (size_t)m * HALF_K + kb * 8) = *(const s8v*)t;
}

// ---- prep: WT[n][k] = bf16(W[k][n])  (W is K x N f32 row-major) ------------
__global__ __launch_bounds__(256) void transpose_cast_kernel(const float* __restrict__ W,
                                                             __hip_bfloat16* __restrict__ WT,
                                                             int K, int N) {
  __shared__ float tile[32][33];
  const int n0 = blockIdx.x * 32, k0 = blockIdx.y * 32;
  const int tx = threadIdx.x & 31;
  const int ty = threadIdx.x >> 5;  // 0..7
#pragma unroll
  for (int i = 0; i < 32; i += 8)
    tile[ty + i][tx] = W[(size_t)(k0 + ty + i) * N + n0 + tx];
  __syncthreads();
#pragma unroll
  for (int i = 0; i < 32; i += 8)
    WT[(size_t)(n0 + ty + i) * K + k0 + tx] = __float2bfloat16(tile[tx][ty + i]);
}

// ---- GEMM: C = A(MxK) @ BT(NxK)^T, 128x128 tile, BK=64, 4 waves ------------
// EPI 0: H[r][c] = bf16(relu(acc + bias[c]))        (H is rows x N bf16)
// EPI 1: zout[r][2c+1] = acc + bias[c]              (stash s in odd cols)
// EPI 2: t = acc+bias; s = zout[r][2c+1]; zout[r][2c..2c+1] = {a, b*exp(s)+t}
template <int EPI>
__global__ __launch_bounds__(256)
void gemm_kernel(const __hip_bfloat16* __restrict__ A,
                 const __hip_bfloat16* __restrict__ BT,
                 const float* __restrict__ bias,
                 const int K, const int N,
                 __hip_bfloat16* __restrict__ H,
                 float* __restrict__ zout,
                 const float* __restrict__ zin) {
  __shared__ alignas(16) char lds[32768];
  char* sA = lds;
  char* sB = lds + 16384;
  const int tid = threadIdx.x;
  const int m0 = blockIdx.x * 128;
  const int n0 = blockIdx.y * 128;

  // staging: LDS is linear [row][64 bf16] but stores swizzled data; the
  // global SOURCE column is pre-swizzled (global_load_lds dest must be linear)
  const int trow = tid >> 3;                                  // 0..31
  const int scol = ((tid & 7) * 16) ^ ((trow & 7) << 4);      // swizzled src byte col
  const char* gA = (const char*)(A + (size_t)(m0 + trow) * K) + scol;
  const char* gB = (const char*)(BT + (size_t)(n0 + trow) * K) + scol;
  char* lA = sA + tid * 16;
  char* lB = sB + tid * 16;
  const size_t rowstep = (size_t)32 * K * 2;  // 32 rows in bytes

  f4v acc[4][4] = {};

  const int lane = tid & 63;
  const int wr = (tid >> 7) & 1;   // wave row (wave = tid>>6; wr = wave>>1)
  const int wc = (tid >> 6) & 1;   // wave col
  const int lr = lane & 15;
  const int lk = lane >> 4;
  const int xorv = (lr & 7) << 4;
  int aoff[4], boff[4];
#pragma unroll
  for (int i = 0; i < 4; ++i) {
    aoff[i] = (wr * 64 + i * 16 + lr) * 128;
    boff[i] = (wc * 64 + i * 16 + lr) * 128;
  }
  const int csw0 = (lk * 16) ^ xorv;        // kk = 0 swizzled col bytes
  const int csw1 = (64 + lk * 16) ^ xorv;   // kk = 1

  for (int k0 = 0; k0 < K; k0 += 64) {
#pragma unroll
    for (int c = 0; c < 4; ++c) gload16(gA + c * rowstep, lA + c * 4096);
#pragma unroll
    for (int c = 0; c < 4; ++c) gload16(gB + c * rowstep, lB + c * 4096);
    gA += 128; gB += 128;
    asm volatile("s_waitcnt vmcnt(0)" ::: "memory");
    __syncthreads();

    s8v af[4], bf[4];
#pragma unroll
    for (int mi = 0; mi < 4; ++mi) af[mi] = *(const s8v*)(sA + aoff[mi] + csw0);
#pragma unroll
    for (int ni = 0; ni < 4; ++ni) bf[ni] = *(const s8v*)(sB + boff[ni] + csw0);
#pragma unroll
    for (int mi = 0; mi < 4; ++mi)
#pragma unroll
      for (int ni = 0; ni < 4; ++ni)
        acc[mi][ni] = __builtin_amdgcn_mfma_f32_16x16x32_bf16(af[mi], bf[ni], acc[mi][ni], 0, 0, 0);
#pragma unroll
    for (int mi = 0; mi < 4; ++mi) af[mi] = *(const s8v*)(sA + aoff[mi] + csw1);
#pragma unroll
    for (int ni = 0; ni < 4; ++ni) bf[ni] = *(const s8v*)(sB + boff[ni] + csw1);
#pragma unroll
    for (int mi = 0; mi < 4; ++mi)
#pragma unroll
      for (int ni = 0; ni < 4; ++ni)
        acc[mi][ni] = __builtin_amdgcn_mfma_f32_16x16x32_bf16(af[mi], bf[ni], acc[mi][ni], 0, 0, 0);
    __syncthreads();
  }

  // epilogue; C/D layout: col = lane&15, row = (lane>>4)*4 + reg   [m89]
#pragma unroll
  for (int mi = 0; mi < 4; ++mi) {
#pragma unroll
    for (int ni = 0; ni < 4; ++ni) {
      const int c = n0 + wc * 64 + ni * 16 + lr;
      const float bv = bias[c];
#pragma unroll
      for (int r = 0; r < 4; ++r) {
        const int rr = m0 + wr * 64 + mi * 16 + lk * 4 + r;
        float v = acc[mi][ni][r] + bv;
        if (EPI == 0) {
          v = fmaxf(v, 0.0f);
          H[(size_t)rr * N + c] = __float2bfloat16(v);
        } else if (EPI == 1) {
          zout[(size_t)rr * DDIM + 2 * c + 1] = v;
        } else {
          const size_t base = (size_t)rr * DDIM + 2 * c;
          float2 ab = *(const float2*)(zin + base);  // {a, b}
          float s = zout[base + 1];
          float2 o;
          o.x = ab.x;
          o.y = ab.y * expf(s) + v;
          *(float2*)(zout + base) = o;
        }
      }
    }
  }
}

// ---- logdet[row] = sum of s (stored in odd cols of zout) -------------------
__global__ __launch_bounds__(256) void logdet_kernel(const float* __restrict__ zout,
                                                     float* __restrict__ ld) {
  const int row = blockIdx.x;
  const int tid = threadIdx.x;
  const float* p = zout + (size_t)row * DDIM;
  float s = p[2 * tid + 1] + p[2 * (tid + 256) + 1];
#pragma unroll
  for (int o = 32; o > 0; o >>= 1) s += __shfl_down(s, o, 64);
  __shared__ float ws4[4];
  if ((tid & 63) == 0) ws4[tid >> 6] = s;
  __syncthreads();
  if (tid == 0) ld[row] = ws4[0] + ws4[1] + ws4[2] + ws4[3];
}

extern "C" void kernel_launch(void* const* d_in, const int* in_sizes, int n_in,
                              void* d_out, int out_size, void* d_ws, size_t ws_size,
                              hipStream_t stream) {
  const float* z   = (const float*)d_in[0];
  const float* W1s = (const float*)d_in[1];
  const float* b1s = (const float*)d_in[2];
  const float* W2s = (const float*)d_in[3];
  const float* b2s = (const float*)d_in[4];
  const float* W1t = (const float*)d_in[5];
  const float* b1t = (const float*)d_in[6];
  const float* W2t = (const float*)d_in[7];
  const float* b2t = (const float*)d_in[8];
  float* zout = (float*)d_out;
  float* ld   = zout + (size_t)BROWS * DDIM;

  char* ws = (char*)d_ws;
  __hip_bfloat16* a16  = (__hip_bfloat16*)ws;                   // 16 MB
  __hip_bfloat16* w1sT = (__hip_bfloat16*)(ws + 16777216);      // 4 MB each
  __hip_bfloat16* w1tT = (__hip_bfloat16*)(ws + 20971520);
  __hip_bfloat16* w2sT = (__hip_bfloat16*)(ws + 25165824);
  __hip_bfloat16* w2tT = (__hip_bfloat16*)(ws + 29360128);
  char* hbase = ws + 33554432;

  // pick largest row-chunk whose H buffers fit the workspace
  int CH = 128;
  for (int c = 16384; c >= 128; c >>= 1) {
    if (33554432ull + (size_t)c * 16384ull <= ws_size) { CH = c; break; }
  }
  __hip_bfloat16* Hs = (__hip_bfloat16*)hbase;
  __hip_bfloat16* Ht = (__hip_bfloat16*)(hbase + (size_t)CH * 8192);

  cast_a_kernel<<<BROWS * (HALF_K / 8) / 256, 256, 0, stream>>>(z, a16);
  transpose_cast_kernel<<<dim3(HID_N / 32, HALF_K / 32), 256, 0, stream>>>(W1s, w1sT, HALF_K, HID_N);
  transpose_cast_kernel<<<dim3(HID_N / 32, HALF_K / 32), 256, 0, stream>>>(W1t, w1tT, HALF_K, HID_N);
  transpose_cast_kernel<<<dim3(HALF_K / 32, HID_N / 32), 256, 0, stream>>>(W2s, w2sT, HID_N, HALF_K);
  transpose_cast_kernel<<<dim3(HALF_K / 32, HID_N / 32), 256, 0, stream>>>(W2t, w2tT, HID_N, HALF_K);

  for (int mb = 0; mb < BROWS; mb += CH) {
    dim3 g1(CH / 128, HID_N / 128);
    gemm_kernel<0><<<g1, 256, 0, stream>>>(a16 + (size_t)mb * HALF_K, w1sT, b1s,
                                           HALF_K, HID_N, Hs, nullptr, nullptr);
    gemm_kernel<0><<<g1, 256, 0, stream>>>(a16 + (size_t)mb * HALF_K, w1tT, b1t,
                                           HALF_K, HID_N, Ht, nullptr, nullptr);
    dim3 g2(CH / 128, HALF_K / 128);
    gemm_kernel<1><<<g2, 256, 0, stream>>>(Hs, w2sT, b2s, HID_N, HALF_K,
                                           nullptr, zout + (size_t)mb * DDIM, nullptr);
    logdet_kernel<<<CH, 256, 0, stream>>>(zout + (size_t)mb * DDIM, ld + mb);
    gemm_kernel<2><<<g2, 256, 0, stream>>>(Ht, w2tT, b2t, HID_N, HALF_K,
                                           nullptr, zout + (size_t)mb * DDIM, z + (size_t)mb * DDIM);
  }
}

// Round 2
// 387.126 us; speedup vs baseline: 1.5692x; 1.5692x over previous
//
#include <hip/hip_runtime.h>
#include <hip/hip_bf16.h>
#include <cstdint>
#include <cstddef>

#define BROWS  16384
#define DDIM   1024
#define HID_N  4096
#define HALF_K 512
#define LDH    8192   // fused H row stride (elements)

typedef __attribute__((ext_vector_type(8))) short s8v;
typedef __attribute__((ext_vector_type(4))) float f4v;

__device__ __forceinline__ void gload16(const void* g, void* l) {
  __builtin_amdgcn_global_load_lds(
      (const __attribute__((address_space(1))) unsigned int*)g,
      (__attribute__((address_space(3))) unsigned int*)l, 16, 0, 0);
}
#define BAR() asm volatile("s_barrier" ::: "memory")

template <int N> __device__ __forceinline__ void vmw() {
  if constexpr (N == 0)      asm volatile("s_waitcnt vmcnt(0)" ::: "memory");
  else if constexpr (N == 3) asm volatile("s_waitcnt vmcnt(3)" ::: "memory");
  else                       asm volatile("s_waitcnt vmcnt(4)" ::: "memory");
}

// ---- prep: a16[m][k] = bf16(z[m][2k]) --------------------------------------
__global__ __launch_bounds__(256) void cast_a_kernel(const float* __restrict__ z,
                                                     __hip_bfloat16* __restrict__ a16) {
  const int idx = blockIdx.x * 256 + threadIdx.x;
  const int m  = idx >> 6;
  const int kb = idx & 63;
  const float4* zp = (const float4*)(z + (size_t)m * DDIM + (size_t)kb * 16);
  alignas(16) __hip_bfloat16 t[8];
#pragma unroll
  for (int i = 0; i < 4; ++i) {
    float4 v = zp[i];
    t[2 * i]     = __float2bfloat16(v.x);
    t[2 * i + 1] = __float2bfloat16(v.z);
  }
  *(s8v*)(a16 + (size_t)m * HALF_K + kb * 8) = *(const s8v*)t;
}

// ---- prep: WT[n][k] = bf16(W[k][n])  (W is K x N f32 row-major) ------------
__global__ __launch_bounds__(256) void transpose_cast_kernel(const float* __restrict__ W,
                                                             __hip_bfloat16* __restrict__ WT,
                                                             int K, int N) {
  __shared__ float tile[32][33];
  const int n0 = blockIdx.x * 32, k0 = blockIdx.y * 32;
  const int tx = threadIdx.x & 31;
  const int ty = threadIdx.x >> 5;
#pragma unroll
  for (int i = 0; i < 32; i += 8)
    tile[ty + i][tx] = W[(size_t)(k0 + ty + i) * N + n0 + tx];
  __syncthreads();
#pragma unroll
  for (int i = 0; i < 32; i += 8)
    WT[(size_t)(n0 + ty + i) * K + k0 + tx] = __float2bfloat16(tile[tx][ty + i]);
}

// ---- 256xBN tile, 8 waves, 4-phase deep-pipelined GEMM ---------------------
// C = A(Mx K) @ BT(N x K)^T.  EPI 0: Hout=bf16(relu(acc+bias)) (ld LDH)
//                             EPI 1: Fout=acc+bias (f32, ld ldo); z-batched.
// Phase q=(qa,qb): A-half qa, B-half qb; MFMA mi in [4qa,4qa+4), ni in
// [qb*NREP/2,...). Stages: q0:B1(T+1) q1:A1(T+1) q2:A0(T+2) q3:B0(T+2);
// one counted vmcnt per K-tile (2+NREP/2), vmcnt(0) only at the tail.
template <int NREP, int EPI>
__global__ __launch_bounds__(512, 2)
void gemm8_kernel(const __hip_bfloat16* A0p, const __hip_bfloat16* BT0,
                  const float* __restrict__ bias00, const float* __restrict__ bias01,
                  int nsplit, int K, int lda, int ldb,
                  __hip_bfloat16* __restrict__ Hout,
                  float* Fout0, int ldo,
                  const __hip_bfloat16* A1p, const __hip_bfloat16* BT1,
                  const float* bias10, float* Fout1) {
  constexpr int BN    = 64 * NREP;
  constexpr int BHALF = (BN / 2) * 128;       // bytes per B half-tile
  constexpr int BUF   = 32768 + 2 * BHALF;    // bytes per K-tile buffer
  __shared__ char smem[2 * BUF];

  const __hip_bfloat16* A  = A0p;
  const __hip_bfloat16* Bt = BT0;
  const float* bias0 = bias00;
  float* Fout = Fout0;
  if (EPI == 1 && blockIdx.z) { A = A1p; Bt = BT1; bias0 = bias10; Fout = Fout1; }

  const int tid = threadIdx.x;
  const int m0 = blockIdx.x * 256;
  const int n0 = blockIdx.y * BN;

  const int trow = tid >> 3;
  const int scol = ((tid & 7) * 16) ^ ((trow & 7) << 4);   // pre-swizzled src col
  const char* Ab = (const char*)A;
  const char* Bb = (const char*)Bt;
  const size_t ldab = (size_t)lda * 2, ldbb = (size_t)ldb * 2;
  const int NT = K >> 6;

  const int lane = tid & 63, wid = tid >> 6;
  const int wr = wid >> 2, wc = wid & 3;
  const int lr = lane & 15, lk = lane >> 4;
  const int xo = (lr & 7) << 4;

  int aoff[4][2], boff[NREP / 2][2];
#pragma unroll
  for (int j = 0; j < 4; ++j)
#pragma unroll
    for (int kk = 0; kk < 2; ++kk)
      aoff[j][kk] = (j * 32 + wr * 16 + lr) * 128 + ((kk * 64 + lk * 16) ^ xo);
#pragma unroll
  for (int nn = 0; nn < NREP / 2; ++nn)
#pragma unroll
    for (int kk = 0; kk < 2; ++kk)
      boff[nn][kk] = (nn * 64 + wc * 16 + lr) * 128 + ((kk * 64 + lk * 16) ^ xo);

  f4v acc[8][NREP] = {};

  auto stage_A = [&](int h, int T) {
#pragma unroll
    for (int l = 0; l < 2; ++l)
      gload16(Ab + (size_t)(m0 + h * 128 + l * 64 + trow) * ldab + (size_t)T * 128 + scol,
              smem + (T & 1) * BUF + h * 16384 + l * 8192 + tid * 16);
  };
  auto stage_B = [&](int h, int T) {
#pragma unroll
    for (int l = 0; l < NREP / 2; ++l)
      gload16(Bb + (size_t)(n0 + h * (BN / 2) + l * 64 + trow) * ldbb + (size_t)T * 128 + scol,
              smem + (T & 1) * BUF + 32768 + h * BHALF + l * 8192 + tid * 16);
  };

  // ---- prologue: tile0 fully + A0/B0 of tile1; leave last 2 halves in flight
  stage_A(0, 0); stage_A(1, 0); stage_B(0, 0); stage_B(1, 0);
  if (NT > 1) { stage_A(0, 1); stage_B(0, 1); vmw<2 + NREP / 2>(); }
  else        { vmw<0>(); }
  BAR();

  for (int T = 0; T < NT; ++T) {
    const char* bufp = smem + (T & 1) * BUF;
    s8v af[4][2], bfr[NREP / 2][2];

    // ---- q0: A half0, B group0; stage B1(T+1)
#pragma unroll
    for (int j = 0; j < 4; ++j) {
      af[j][0] = *(const s8v*)(bufp + aoff[j][0]);
      af[j][1] = *(const s8v*)(bufp + aoff[j][1]);
    }
#pragma unroll
    for (int nn = 0; nn < NREP / 2; ++nn) {
      bfr[nn][0] = *(const s8v*)(bufp + 32768 + boff[nn][0]);
      bfr[nn][1] = *(const s8v*)(bufp + 32768 + boff[nn][1]);
    }
    if (T + 1 < NT) stage_B(1, T + 1);
    BAR();
    __builtin_amdgcn_sched_barrier(0);
    __builtin_amdgcn_s_setprio(1);
#pragma unroll
    for (int j = 0; j < 4; ++j)
#pragma unroll
      for (int nn = 0; nn < NREP / 2; ++nn)
#pragma unroll
        for (int kk = 0; kk < 2; ++kk)
          acc[j][nn] = __builtin_amdgcn_mfma_f32_16x16x32_bf16(af[j][kk], bfr[nn][kk], acc[j][nn], 0, 0, 0);
    __builtin_amdgcn_s_setprio(0);
    BAR();

    // ---- q1: B group1; stage A1(T+1)
#pragma unroll
    for (int nn = 0; nn < NREP / 2; ++nn) {
      bfr[nn][0] = *(const s8v*)(bufp + 32768 + BHALF + boff[nn][0]);
      bfr[nn][1] = *(const s8v*)(bufp + 32768 + BHALF + boff[nn][1]);
    }
    if (T + 1 < NT) stage_A(1, T + 1);
    BAR();
    __builtin_amdgcn_sched_barrier(0);
    __builtin_amdgcn_s_setprio(1);
#pragma unroll
    for (int j = 0; j < 4; ++j)
#pragma unroll
      for (int nn = 0; nn < NREP / 2; ++nn)
#pragma unroll
        for (int kk = 0; kk < 2; ++kk)
          acc[j][NREP / 2 + nn] = __builtin_amdgcn_mfma_f32_16x16x32_bf16(af[j][kk], bfr[nn][kk], acc[j][NREP / 2 + nn], 0, 0, 0);
    __builtin_amdgcn_s_setprio(0);
    BAR();

    // ---- q2: A half1, B group0; stage A0(T+2)
#pragma unroll
    for (int j = 0; j < 4; ++j) {
      af[j][0] = *(const s8v*)(bufp + 16384 + aoff[j][0]);
      af[j][1] = *(const s8v*)(bufp + 16384 + aoff[j][1]);
    }
#pragma unroll
    for (int nn = 0; nn < NREP / 2; ++nn) {
      bfr[nn][0] = *(const s8v*)(bufp + 32768 + boff[nn][0]);
      bfr[nn][1] = *(const s8v*)(bufp + 32768 + boff[nn][1]);
    }
    if (T + 2 < NT) stage_A(0, T + 2);
    BAR();
    __builtin_amdgcn_sched_barrier(0);
    __builtin_amdgcn_s_setprio(1);
#pragma unroll
    for (int j = 0; j < 4; ++j)
#pragma unroll
      for (int nn = 0; nn < NREP / 2; ++nn)
#pragma unroll
        for (int kk = 0; kk < 2; ++kk)
          acc[4 + j][nn] = __builtin_amdgcn_mfma_f32_16x16x32_bf16(af[j][kk], bfr[nn][kk], acc[4 + j][nn], 0, 0, 0);
    __builtin_amdgcn_s_setprio(0);
    BAR();

    // ---- q3: B group1; stage B0(T+2); tile-boundary counted vmcnt
#pragma unroll
    for (int nn = 0; nn < NREP / 2; ++nn) {
      bfr[nn][0] = *(const s8v*)(bufp + 32768 + BHALF + boff[nn][0]);
      bfr[nn][1] = *(const s8v*)(bufp + 32768 + BHALF + boff[nn][1]);
    }
    if (T + 2 < NT) stage_B(0, T + 2);
    BAR();
    __builtin_amdgcn_sched_barrier(0);
    __builtin_amdgcn_s_setprio(1);
#pragma unroll
    for (int j = 0; j < 4; ++j)
#pragma unroll
      for (int nn = 0; nn < NREP / 2; ++nn)
#pragma unroll
        for (int kk = 0; kk < 2; ++kk)
          acc[4 + j][NREP / 2 + nn] = __builtin_amdgcn_mfma_f32_16x16x32_bf16(af[j][kk], bfr[nn][kk], acc[4 + j][NREP / 2 + nn], 0, 0, 0);
    __builtin_amdgcn_s_setprio(0);
    if (T + 2 >= NT) vmw<0>(); else vmw<2 + NREP / 2>();
    BAR();
  }

  // ---- epilogue; C/D layout: col = lane&15, row = (lane>>4)*4 + reg
#pragma unroll
  for (int ni = 0; ni < NREP; ++ni) {
    const int c = n0 + ni * 64 + wc * 16 + lr;
    const float bv = (EPI == 0 && c >= nsplit) ? bias01[c - nsplit] : bias0[EPI == 0 && c >= nsplit ? 0 : c];
#pragma unroll
    for (int mi = 0; mi < 8; ++mi) {
#pragma unroll
      for (int r = 0; r < 4; ++r) {
        const int rr = m0 + mi * 32 + wr * 16 + lk * 4 + r;
        float v = acc[mi][ni][r] + bv;
        if (EPI == 0) {
          Hout[(size_t)rr * LDH + c] = __float2bfloat16(fmaxf(v, 0.0f));
        } else {
          Fout[(size_t)rr * ldo + c] = v;
        }
      }
    }
  }
}

// ---- finish: zout interleave, b*exp(s)+t, per-row logdet -------------------
__global__ __launch_bounds__(256) void finish_kernel(const float* __restrict__ z,
                                                     const float* __restrict__ s,
                                                     const float* __restrict__ t,
                                                     float* __restrict__ zout,
                                                     float* __restrict__ ld) {
  const int row = blockIdx.x;
  const int tid = threadIdx.x;
  const float* zr = z + (size_t)row * DDIM;
  float* zo = zout + (size_t)row * DDIM;
  const float* sr = s + (size_t)row * 512;
  const float* tr = t + (size_t)row * 512;
  float acc = 0.0f;
#pragma unroll
  for (int i = 0; i < 2; ++i) {
    const int j = tid + i * 256;
    float2 zv = *(const float2*)(zr + 2 * j);
    float sv = sr[j], tv = tr[j];
    acc += sv;
    float2 o;
    o.x = zv.x;
    o.y = zv.y * expf(sv) + tv;
    *(float2*)(zo + 2 * j) = o;
  }
#pragma unroll
  for (int o = 32; o > 0; o >>= 1) acc += __shfl_down(acc, o, 64);
  __shared__ float w4[4];
  if ((tid & 63) == 0) w4[tid >> 6] = acc;
  __syncthreads();
  if (tid == 0) ld[row] = w4[0] + w4[1] + w4[2] + w4[3];
}

extern "C" void kernel_launch(void* const* d_in, const int* in_sizes, int n_in,
                              void* d_out, int out_size, void* d_ws, size_t ws_size,
                              hipStream_t stream) {
  const float* z   = (const float*)d_in[0];
  const float* W1s = (const float*)d_in[1];
  const float* b1s = (const float*)d_in[2];
  const float* W2s = (const float*)d_in[3];
  const float* b2s = (const float*)d_in[4];
  const float* W1t = (const float*)d_in[5];
  const float* b1t = (const float*)d_in[6];
  const float* W2t = (const float*)d_in[7];
  const float* b2t = (const float*)d_in[8];
  float* zout = (float*)d_out;
  float* ld   = zout + (size_t)BROWS * DDIM;

  char* ws = (char*)d_ws;
  __hip_bfloat16* a16    = (__hip_bfloat16*)ws;                    // 16 MB
  __hip_bfloat16* w1catT = (__hip_bfloat16*)(ws + 16777216);       // 8 MB
  __hip_bfloat16* w2sT   = (__hip_bfloat16*)(ws + 25165824);       // 4 MB
  __hip_bfloat16* w2tT   = (__hip_bfloat16*)(ws + 29360128);       // 4 MB
  float*          st0    = (float*)(ws + 33554432);                // 32 MB
  float*          st1    = (float*)(ws + 67108864);                // 32 MB
  char*           hbase  = ws + 100663296;

  int CH = 256;
  for (int c = 16384; c >= 256; c >>= 1) {
    if (100663296ull + (size_t)c * 16384ull <= ws_size) { CH = c; break; }
  }
  __hip_bfloat16* H = (__hip_bfloat16*)hbase;   // CH x 8192 bf16

  cast_a_kernel<<<BROWS * (HALF_K / 8) / 256, 256, 0, stream>>>(z, a16);
  transpose_cast_kernel<<<dim3(128, 16), 256, 0, stream>>>(W1s, w1catT, HALF_K, HID_N);
  transpose_cast_kernel<<<dim3(128, 16), 256, 0, stream>>>(W1t, w1catT + (size_t)HID_N * HALF_K, HALF_K, HID_N);
  transpose_cast_kernel<<<dim3(16, 128), 256, 0, stream>>>(W2s, w2sT, HID_N, HALF_K);
  transpose_cast_kernel<<<dim3(16, 128), 256, 0, stream>>>(W2t, w2tT, HID_N, HALF_K);

  for (int mb = 0; mb < BROWS; mb += CH) {
    // G1: [CH x 512] @ [8192 x 512]^T -> H (relu, bf16), bias = b1s|b1t
    gemm8_kernel<4, 0><<<dim3(CH / 256, 32, 1), 512, 0, stream>>>(
        a16 + (size_t)mb * HALF_K, w1catT, b1s, b1t, HID_N,
        HALF_K, HALF_K, HALF_K, H, nullptr, 0, nullptr, nullptr, nullptr, nullptr);
    // G2 (z-batched): [CH x 4096] @ [512 x 4096]^T -> st (f32)
    gemm8_kernel<2, 1><<<dim3(CH / 256, 4, 2), 512, 0, stream>>>(
        H, w2sT, b2s, nullptr, 1 << 30,
        HID_N, LDH, HID_N, nullptr, st0 + (size_t)mb * HALF_K, HALF_K,
        H + HID_N, w2tT, b2t, st1 + (size_t)mb * HALF_K);
  }
  finish_kernel<<<BROWS, 256, 0, stream>>>(z, st0, st1, zout, ld);
}

// Round 5
// 370.444 us; speedup vs baseline: 1.6399x; 1.0450x over previous
//
#include <hip/hip_runtime.h>
#include <hip/hip_bf16.h>
#include <cstdint>
#include <cstddef>

#define BROWS  16384
#define DDIM   1024
#define HID_N  4096
#define HALF_K 512
#define LDH    8192   // fused H row stride (elements)

typedef __attribute__((ext_vector_type(8))) short s8v;
typedef __attribute__((ext_vector_type(4))) float f4v;

__device__ __forceinline__ void gload16(const void* g, void* l) {
  __builtin_amdgcn_global_load_lds(
      (const __attribute__((address_space(1))) unsigned int*)g,
      (__attribute__((address_space(3))) unsigned int*)l, 16, 0, 0);
}
#define BAR()   asm volatile("s_barrier" ::: "memory")
// barrier with LDS-op drain (explicit ds_write -> cross-wave ds_read handoff)
#define BARS()  asm volatile("s_waitcnt lgkmcnt(0)\n\ts_barrier" ::: "memory")
#define SCHED0() __builtin_amdgcn_sched_barrier(0)

template <int N> __device__ __forceinline__ void vmw() {
  if constexpr (N == 0)      asm volatile("s_waitcnt vmcnt(0)" ::: "memory");
  else if constexpr (N == 4) asm volatile("s_waitcnt vmcnt(4)" ::: "memory");
  else if constexpr (N == 8) asm volatile("s_waitcnt vmcnt(8)" ::: "memory");
}

// ---- prep: a16[m][k] = bf16(z[m][2k]) --------------------------------------
__global__ __launch_bounds__(256) void cast_a_kernel(const float* __restrict__ z,
                                                     __hip_bfloat16* __restrict__ a16) {
  const int idx = blockIdx.x * 256 + threadIdx.x;
  const int m  = idx >> 6;
  const int kb = idx & 63;
  const float4* zp = (const float4*)(z + (size_t)m * DDIM + (size_t)kb * 16);
  alignas(16) __hip_bfloat16 t[8];
#pragma unroll
  for (int i = 0; i < 4; ++i) {
    float4 v = zp[i];
    t[2 * i]     = __float2bfloat16(v.x);
    t[2 * i + 1] = __float2bfloat16(v.z);
  }
  *(s8v*)(a16 + (size_t)m * HALF_K + kb * 8) = *(const s8v*)t;
}

// ---- prep: WT[n][k] = bf16(W[k][n])  (W is K x N f32 row-major) ------------
__global__ __launch_bounds__(256) void transpose_cast_kernel(const float* __restrict__ W,
                                                             __hip_bfloat16* __restrict__ WT,
                                                             int K, int N) {
  __shared__ float tile[32][33];
  const int n0 = blockIdx.x * 32, k0 = blockIdx.y * 32;
  const int tx = threadIdx.x & 31;
  const int ty = threadIdx.x >> 5;
#pragma unroll
  for (int i = 0; i < 32; i += 8)
    tile[ty + i][tx] = W[(size_t)(k0 + ty + i) * N + n0 + tx];
  __syncthreads();
#pragma unroll
  for (int i = 0; i < 32; i += 8)
    WT[(size_t)(n0 + ty + i) * K + k0 + tx] = __float2bfloat16(tile[tx][ty + i]);
}

// ---- G1: [CH x 512] @ [8192 x 512]^T -> H bf16 (relu, bias b1s|b1t) --------
// 256x256 tile, 8 waves, 4-phase, counted vmcnt(4)/tile, no B re-reads,
// LDS-bounce coalesced epilogue.
__global__ __launch_bounds__(512, 2)
void gemm1_kernel(const __hip_bfloat16* __restrict__ A,
                  const __hip_bfloat16* __restrict__ BT,
                  const float* __restrict__ b1s, const float* __restrict__ b1t,
                  __hip_bfloat16* __restrict__ Hout) {
  __shared__ alignas(16) char smem[131072];   // 2 x (A 32KB + B 32KB)
  constexpr int NT = HALF_K / 64;             // 8

  const int nwg = gridDim.x;
  const int orig = blockIdx.x;
  const int vid = (orig & 7) * (nwg >> 3) + (orig >> 3);  // XCD-chunked
  const int bx = vid >> 5, by = vid & 31;
  const int m0 = bx * 256, n0 = by * 256;

  const int tid = threadIdx.x;
  const int trow = tid >> 3;
  const int scol = ((tid & 7) * 16) ^ ((trow & 7) << 4);

  const int lane = tid & 63, wid = tid >> 6;
  const int wr = wid >> 2, wc = wid & 3;
  const int lr = lane & 15, lk = lane >> 4;
  const int xo = (lr & 7) << 4;

  int aoff[4][2], boff[2][2];
#pragma unroll
  for (int j = 0; j < 4; ++j)
#pragma unroll
    for (int kk = 0; kk < 2; ++kk)
      aoff[j][kk] = (j * 32 + wr * 16 + lr) * 128 + ((kk * 64 + lk * 16) ^ xo);
#pragma unroll
  for (int nn = 0; nn < 2; ++nn)
#pragma unroll
    for (int kk = 0; kk < 2; ++kk)
      boff[nn][kk] = (nn * 64 + wc * 16 + lr) * 128 + ((kk * 64 + lk * 16) ^ xo);

  f4v acc[8][4] = {};

  auto stage_A = [&](int h, int T) {
#pragma unroll
    for (int l = 0; l < 2; ++l)
      gload16((const char*)A + (size_t)(m0 + h * 128 + l * 64 + trow) * (HALF_K * 2) + (size_t)T * 128 + scol,
              smem + (T & 1) * 65536 + h * 16384 + l * 8192 + tid * 16);
  };
  auto stage_B = [&](int h, int T) {
#pragma unroll
    for (int l = 0; l < 2; ++l)
      gload16((const char*)BT + (size_t)(n0 + h * 128 + l * 64 + trow) * (HALF_K * 2) + (size_t)T * 128 + scol,
              smem + (T & 1) * 65536 + 32768 + h * 16384 + l * 8192 + tid * 16);
  };

  // prologue: tile0 fully + A0/B0 of tile1 (12 gloads); vmcnt(4) -> tile0 done
  stage_A(0, 0); stage_B(0, 0); stage_A(1, 0); stage_B(1, 0);
  stage_A(0, 1); stage_B(0, 1);
  vmw<4>();
  BAR();

  for (int T = 0; T < NT; ++T) {
    const char* bufp = smem + (T & 1) * 65536;
    s8v af[4][2], b0r[2][2], b1r[2][2];

    // q0: read A0 + B0; stage B1(T+1); MFMA acc[0..3][0..1]
#pragma unroll
    for (int j = 0; j < 4; ++j) {
      af[j][0] = *(const s8v*)(bufp + aoff[j][0]);
      af[j][1] = *(const s8v*)(bufp + aoff[j][1]);
    }
#pragma unroll
    for (int nn = 0; nn < 2; ++nn) {
      b0r[nn][0] = *(const s8v*)(bufp + 32768 + boff[nn][0]);
      b0r[nn][1] = *(const s8v*)(bufp + 32768 + boff[nn][1]);
    }
    if (T + 1 < NT) stage_B(1, T + 1);
    BAR(); SCHED0();
    __builtin_amdgcn_s_setprio(1);
#pragma unroll
    for (int j = 0; j < 4; ++j)
#pragma unroll
      for (int nn = 0; nn < 2; ++nn)
#pragma unroll
        for (int kk = 0; kk < 2; ++kk)
          acc[j][nn] = __builtin_amdgcn_mfma_f32_16x16x32_bf16(af[j][kk], b0r[nn][kk], acc[j][nn], 0, 0, 0);
    __builtin_amdgcn_s_setprio(0);
    BAR();

    // q1: read B1; stage A1(T+1); MFMA acc[0..3][2..3]
#pragma unroll
    for (int nn = 0; nn < 2; ++nn) {
      b1r[nn][0] = *(const s8v*)(bufp + 49152 + boff[nn][0]);
      b1r[nn][1] = *(const s8v*)(bufp + 49152 + boff[nn][1]);
    }
    if (T + 1 < NT) stage_A(1, T + 1);
    BAR(); SCHED0();
    __builtin_amdgcn_s_setprio(1);
#pragma unroll
    for (int j = 0; j < 4; ++j)
#pragma unroll
      for (int nn = 0; nn < 2; ++nn)
#pragma unroll
        for (int kk = 0; kk < 2; ++kk)
          acc[j][2 + nn] = __builtin_amdgcn_mfma_f32_16x16x32_bf16(af[j][kk], b1r[nn][kk], acc[j][2 + nn], 0, 0, 0);
    __builtin_amdgcn_s_setprio(0);
    BAR();

    // q2: read A1 (overwrite af); stage A0(T+2); MFMA acc[4..7][0..1] (B0 regs)
#pragma unroll
    for (int j = 0; j < 4; ++j) {
      af[j][0] = *(const s8v*)(bufp + 16384 + aoff[j][0]);
      af[j][1] = *(const s8v*)(bufp + 16384 + aoff[j][1]);
    }
    if (T + 2 < NT) stage_A(0, T + 2);
    BAR(); SCHED0();
    __builtin_amdgcn_s_setprio(1);
#pragma unroll
    for (int j = 0; j < 4; ++j)
#pragma unroll
      for (int nn = 0; nn < 2; ++nn)
#pragma unroll
        for (int kk = 0; kk < 2; ++kk)
          acc[4 + j][nn] = __builtin_amdgcn_mfma_f32_16x16x32_bf16(af[j][kk], b0r[nn][kk], acc[4 + j][nn], 0, 0, 0);
    __builtin_amdgcn_s_setprio(0);
    BAR();

    // q3: no reads; stage B0(T+2); MFMA acc[4..7][2..3] (B1 regs); vmcnt
    if (T + 2 < NT) stage_B(0, T + 2);
    SCHED0();
    __builtin_amdgcn_s_setprio(1);
#pragma unroll
    for (int j = 0; j < 4; ++j)
#pragma unroll
      for (int nn = 0; nn < 2; ++nn)
#pragma unroll
        for (int kk = 0; kk < 2; ++kk)
          acc[4 + j][2 + nn] = __builtin_amdgcn_mfma_f32_16x16x32_bf16(af[j][kk], b1r[nn][kk], acc[4 + j][2 + nn], 0, 0, 0);
    __builtin_amdgcn_s_setprio(0);
    if (T + 2 >= NT) vmw<0>(); else vmw<4>();
    BAR();
  }

  // ---- epilogue: bias+relu+bf16 -> LDS (swizzled) -> coalesced 16B stores
  const float* bp = (n0 < HID_N) ? b1s : b1t;
  const int cb0 = n0 & (HID_N - 1);
  float bv[4];
#pragma unroll
  for (int ni = 0; ni < 4; ++ni) bv[ni] = bp[cb0 + ni * 64 + wc * 16 + lr];
  const int rbase = wr * 16 + lk * 4;

#pragma unroll
  for (int mi = 0; mi < 8; ++mi) {
    BARS();   // prior readback (lgkm) must drain before overwrite
#pragma unroll
    for (int ni = 0; ni < 4; ++ni) {
      const int cb = (ni * 64 + wc * 16 + lr) * 2;
#pragma unroll
      for (int r = 0; r < 4; ++r) {
        const int row = rbase + r;
        float v = fmaxf(acc[mi][ni][r] + bv[ni], 0.0f);
        *(__hip_bfloat16*)(smem + row * 512 + (cb ^ ((row & 7) << 4))) = __float2bfloat16(v);
      }
    }
    BARS();   // ds_writes must land before other waves' ds_reads
#pragma unroll
    for (int i = 0; i < 2; ++i) {
      const int bo = tid * 32 + i * 16;
      const int row = bo >> 9, cb = bo & 511;
      s8v v = *(const s8v*)(smem + row * 512 + (cb ^ ((row & 7) << 4)));
      *(s8v*)((char*)Hout + ((size_t)(m0 + mi * 32 + row) * LDH + n0) * 2 + cb) = v;
    }
  }
}

// ---- G2 fused: s = Hs@W2s^T+b2s, t = Ht@W2t^T+b2t (SEPARATE A streams!) ----
// 128 rows x 128 cols (s and t at same cols), 8 waves, 2-phase, vmcnt(8).
// Epilogue: zout interleave b*exp(s)+t, logdet partials.
__global__ __launch_bounds__(512, 2)
void gemm2_kernel(const __hip_bfloat16* __restrict__ H,
                  const __hip_bfloat16* __restrict__ BsT,
                  const __hip_bfloat16* __restrict__ BtT,
                  const float* __restrict__ b2s, const float* __restrict__ b2t,
                  const float* __restrict__ zin, float* __restrict__ zout,
                  float* __restrict__ gpart) {
  __shared__ alignas(16) char smem[131072];   // 2 x (As|At|Bs|Bt, 16KB each)
  constexpr int NT = HID_N / 64;              // 64

  const int nwg = gridDim.x;
  const int orig = blockIdx.x;
  const int vid = (orig & 7) * (nwg >> 3) + (orig >> 3);
  const int rb = vid >> 2, by = vid & 3;
  const int m0 = rb * 128, n0c = by * 128;

  const int tid = threadIdx.x;
  const int trow = tid >> 3;
  const int scol = ((tid & 7) * 16) ^ ((trow & 7) << 4);

  const int lane = tid & 63, wid = tid >> 6;
  const int wr = wid >> 2, wc = wid & 3;
  const int lr = lane & 15, lk = lane >> 4;
  const int xo = (lr & 7) << 4;

  int aoff[4][2], boff[2][2];
#pragma unroll
  for (int j = 0; j < 4; ++j)
#pragma unroll
    for (int kk = 0; kk < 2; ++kk)
      aoff[j][kk] = (j * 32 + wr * 16 + lr) * 128 + ((kk * 64 + lk * 16) ^ xo);
#pragma unroll
  for (int nn = 0; nn < 2; ++nn)
#pragma unroll
    for (int kk = 0; kk < 2; ++kk)
      boff[nn][kk] = (nn * 64 + wc * 16 + lr) * 128 + ((kk * 64 + lk * 16) ^ xo);

  f4v as[4][2] = {}, at[4][2] = {};

  // H byte row stride = LDH*2; t-half of H starts at byte col 8192.
  auto stage_As = [&](int T) {
#pragma unroll
    for (int l = 0; l < 2; ++l)
      gload16((const char*)H + (size_t)(m0 + l * 64 + trow) * (LDH * 2) + (size_t)T * 128 + scol,
              smem + (T & 1) * 65536 + l * 8192 + tid * 16);
  };
  auto stage_At = [&](int T) {
#pragma unroll
    for (int l = 0; l < 2; ++l)
      gload16((const char*)H + (size_t)(m0 + l * 64 + trow) * (LDH * 2) + 8192 + (size_t)T * 128 + scol,
              smem + (T & 1) * 65536 + 16384 + l * 8192 + tid * 16);
  };
  auto stage_Bs = [&](int T) {
#pragma unroll
    for (int l = 0; l < 2; ++l)
      gload16((const char*)BsT + (size_t)(n0c + l * 64 + trow) * (HID_N * 2) + (size_t)T * 128 + scol,
              smem + (T & 1) * 65536 + 32768 + l * 8192 + tid * 16);
  };
  auto stage_Bt = [&](int T) {
#pragma unroll
    for (int l = 0; l < 2; ++l)
      gload16((const char*)BtT + (size_t)(n0c + l * 64 + trow) * (HID_N * 2) + (size_t)T * 128 + scol,
              smem + (T & 1) * 65536 + 49152 + l * 8192 + tid * 16);
  };

  // prologue (12 loads): As0,Bs0 | At0,Bt0 | As1,Bs1; vmcnt(8) -> As0,Bs0 done
  stage_As(0); stage_Bs(0); stage_At(0); stage_Bt(0); stage_As(1); stage_Bs(1);
  vmw<8>();
  BAR();

  // invariant at q0(T) entry: outstanding = {At(T),Bt(T),As(T+1),Bs(T+1)};
  // As(T),Bs(T) landed.
  for (int T = 0; T < NT; ++T) {
    const char* bufp = smem + (T & 1) * 65536;
    s8v af[4][2], bfr[2][2];

    // q0: read As[T],Bs[T]; stage At(T+1),Bt(T+1); MFMA s; vmcnt(8)->At,Bt[T]
#pragma unroll
    for (int j = 0; j < 4; ++j) {
      af[j][0] = *(const s8v*)(bufp + aoff[j][0]);
      af[j][1] = *(const s8v*)(bufp + aoff[j][1]);
    }
#pragma unroll
    for (int nn = 0; nn < 2; ++nn) {
      bfr[nn][0] = *(const s8v*)(bufp + 32768 + boff[nn][0]);
      bfr[nn][1] = *(const s8v*)(bufp + 32768 + boff[nn][1]);
    }
    if (T + 1 < NT) { stage_At(T + 1); stage_Bt(T + 1); }
    BAR(); SCHED0();
    __builtin_amdgcn_s_setprio(1);
#pragma unroll
    for (int j = 0; j < 4; ++j)
#pragma unroll
      for (int nn = 0; nn < 2; ++nn)
#pragma unroll
        for (int kk = 0; kk < 2; ++kk)
          as[j][nn] = __builtin_amdgcn_mfma_f32_16x16x32_bf16(af[j][kk], bfr[nn][kk], as[j][nn], 0, 0, 0);
    __builtin_amdgcn_s_setprio(0);
    if (T + 1 >= NT) vmw<0>(); else vmw<8>();
    BAR();

    // q1: read At[T],Bt[T]; stage As(T+2),Bs(T+2); MFMA t; vmcnt(8)->As,Bs[T+1]
#pragma unroll
    for (int j = 0; j < 4; ++j) {
      af[j][0] = *(const s8v*)(bufp + 16384 + aoff[j][0]);
      af[j][1] = *(const s8v*)(bufp + 16384 + aoff[j][1]);
    }
#pragma unroll
    for (int nn = 0; nn < 2; ++nn) {
      bfr[nn][0] = *(const s8v*)(bufp + 49152 + boff[nn][0]);
      bfr[nn][1] = *(const s8v*)(bufp + 49152 + boff[nn][1]);
    }
    if (T + 2 < NT) { stage_As(T + 2); stage_Bs(T + 2); }
    BAR(); SCHED0();
    __builtin_amdgcn_s_setprio(1);
#pragma unroll
    for (int j = 0; j < 4; ++j)
#pragma unroll
      for (int nn = 0; nn < 2; ++nn)
#pragma unroll
        for (int kk = 0; kk < 2; ++kk)
          at[j][nn] = __builtin_amdgcn_mfma_f32_16x16x32_bf16(af[j][kk], bfr[nn][kk], at[j][nn], 0, 0, 0);
    __builtin_amdgcn_s_setprio(0);
    if (T + 2 >= NT) vmw<0>(); else vmw<8>();
    BAR();
  }

  // ---- fused epilogue: b*exp(s)+t, interleaved zout, logdet partials
  float bvs[2], bvt[2];
#pragma unroll
  for (int ni = 0; ni < 2; ++ni) {
    const int c = n0c + ni * 64 + wc * 16 + lr;
    bvs[ni] = b2s[c];
    bvt[ni] = b2t[c];
  }
  float pl[4][4] = {};
#pragma unroll
  for (int mi = 0; mi < 4; ++mi) {
#pragma unroll
    for (int ni = 0; ni < 2; ++ni) {
      const int cg = n0c + ni * 64 + wc * 16 + lr;
#pragma unroll
      for (int r = 0; r < 4; ++r) {
        const int rr = m0 + mi * 32 + wr * 16 + lk * 4 + r;
        const float sv = as[mi][ni][r] + bvs[ni];
        const float tv = at[mi][ni][r] + bvt[ni];
        pl[mi][r] += sv;
        const size_t base = (size_t)rr * DDIM + 2 * cg;
        float2 zv = *(const float2*)(zin + base);
        float2 o;
        o.x = zv.x;
        o.y = zv.y * __expf(sv) + tv;
        *(float2*)(zout + base) = o;
      }
    }
  }
  // reduce pl across the 16 lr-lanes (rows depend only on lk, not lr)
#pragma unroll
  for (int m = 1; m < 16; m <<= 1)
#pragma unroll
    for (int mi = 0; mi < 4; ++mi)
#pragma unroll
      for (int r = 0; r < 4; ++r)
        pl[mi][r] += __shfl_xor(pl[mi][r], m, 64);

  float (*ldp)[4] = (float (*)[4])smem;   // [128][4]
  BARS();   // main-loop LDS traffic drained before reuse
  if (lr == 0) {
#pragma unroll
    for (int mi = 0; mi < 4; ++mi)
#pragma unroll
      for (int r = 0; r < 4; ++r)
        ldp[mi * 32 + wr * 16 + lk * 4 + r][wc] = pl[mi][r];
  }
  BARS();   // ds_writes visible before cross-wave ds_reads
  if (tid < 128) {
    float v = ldp[tid][0] + ldp[tid][1] + ldp[tid][2] + ldp[tid][3];
    gpart[(size_t)(m0 + tid) * 4 + by] = v;
  }
}

// ---- ld[row] = sum of 4 partials (fixed order) -----------------------------
__global__ __launch_bounds__(256) void ld_reduce_kernel(const float* __restrict__ gpart,
                                                        float* __restrict__ ld) {
  const int r = blockIdx.x * 256 + threadIdx.x;
  float4 v = ((const float4*)gpart)[r];
  ld[r] = v.x + v.y + v.z + v.w;
}

extern "C" void kernel_launch(void* const* d_in, const int* in_sizes, int n_in,
                              void* d_out, int out_size, void* d_ws, size_t ws_size,
                              hipStream_t stream) {
  const float* z   = (const float*)d_in[0];
  const float* W1s = (const float*)d_in[1];
  const float* b1s = (const float*)d_in[2];
  const float* W2s = (const float*)d_in[3];
  const float* b2s = (const float*)d_in[4];
  const float* W1t = (const float*)d_in[5];
  const float* b1t = (const float*)d_in[6];
  const float* W2t = (const float*)d_in[7];
  const float* b2t = (const float*)d_in[8];
  float* zout = (float*)d_out;
  float* ld   = zout + (size_t)BROWS * DDIM;

  char* ws = (char*)d_ws;
  __hip_bfloat16* a16    = (__hip_bfloat16*)ws;                    // 16 MB
  __hip_bfloat16* w1catT = (__hip_bfloat16*)(ws + 16777216);       // 8 MB
  __hip_bfloat16* w2sT   = (__hip_bfloat16*)(ws + 25165824);       // 4 MB
  __hip_bfloat16* w2tT   = (__hip_bfloat16*)(ws + 29360128);       // 4 MB
  float*          gpart  = (float*)(ws + 33554432);                // 256 KB
  char*           hbase  = ws + 33816576;

  // chunk rows: cap at 8192 so the H chunk (134 MB) stays L3-resident
  int CH = 2048;
  for (int c = 8192; c >= 2048; c >>= 1) {
    if (33816576ull + (size_t)c * 16384ull <= ws_size) { CH = c; break; }
  }
  __hip_bfloat16* H = (__hip_bfloat16*)hbase;   // CH x 8192 bf16

  cast_a_kernel<<<BROWS * (HALF_K / 8) / 256, 256, 0, stream>>>(z, a16);
  transpose_cast_kernel<<<dim3(128, 16), 256, 0, stream>>>(W1s, w1catT, HALF_K, HID_N);
  transpose_cast_kernel<<<dim3(128, 16), 256, 0, stream>>>(W1t, w1catT + (size_t)HID_N * HALF_K, HALF_K, HID_N);
  transpose_cast_kernel<<<dim3(16, 128), 256, 0, stream>>>(W2s, w2sT, HID_N, HALF_K);
  transpose_cast_kernel<<<dim3(16, 128), 256, 0, stream>>>(W2t, w2tT, HID_N, HALF_K);

  for (int mb = 0; mb < BROWS; mb += CH) {
    gemm1_kernel<<<(CH / 256) * 32, 512, 0, stream>>>(
        a16 + (size_t)mb * HALF_K, w1catT, b1s, b1t, H);
    gemm2_kernel<<<(CH / 128) * 4, 512, 0, stream>>>(
        H, w2sT, w2tT, b2s, b2t,
        z + (size_t)mb * DDIM, zout + (size_t)mb * DDIM, gpart + (size_t)mb * 4);
  }
  ld_reduce_kernel<<<BROWS / 256, 256, 0, stream>>>(gpart, ld);
}